// Round 8
// baseline (368.118 us; speedup 1.0000x reference)
//
#include <hip/hip_runtime.h>
#include <stdint.h>

typedef unsigned short u16;
typedef __bf16 bf16x8 __attribute__((ext_vector_type(8)));
typedef __bf16 bf16x2 __attribute__((ext_vector_type(2)));
typedef short s16x4 __attribute__((ext_vector_type(4)));
typedef float f32x4 __attribute__((ext_vector_type(4)));

typedef __attribute__((address_space(1))) void gvoid_t;
typedef __attribute__((address_space(3))) void lvoid_t;

struct alignas(16) U128 { uint32_t x, y, z, w; };
struct alignas(16) F128 { float x, y, z, w; };
struct alignas(8)  U64v { uint32_t x, y; };

__device__ __forceinline__ void gld16(const u16* g, u16* lds) {
  __builtin_amdgcn_global_load_lds((gvoid_t*)const_cast<u16*>(g),
                                   (lvoid_t*)lds, 16, 0, 0);
}

__device__ __forceinline__ u16 f2bf(float f) {
  uint32_t u = __builtin_bit_cast(uint32_t, f);
  u += 0x7FFFu + ((u >> 16) & 1u);   // RNE
  return (u16)(u >> 16);
}
__device__ __forceinline__ float bf2f(u16 h) {
  return __builtin_bit_cast(float, (uint32_t)h << 16);
}
__device__ __forceinline__ bf16x8 ldfrag(const u16* p) {
  U128 u = *reinterpret_cast<const U128*>(p);
  return __builtin_bit_cast(bf16x8, u);
}
// concat two 4x-bf16 halves into one 8x-bf16 MFMA fragment (no shuffles)
__device__ __forceinline__ bf16x8 cat8(U64v lo, U64v hi) {
  U128 u; u.x = lo.x; u.y = lo.y; u.z = hi.x; u.w = hi.y;
  return __builtin_bit_cast(bf16x8, u);
}
// pack two f32 -> bf16x2 dword via HW cvt (compiler emits v_cvt_pk_bf16_f32)
__device__ __forceinline__ uint32_t pkbf(float a, float b) {
  bf16x2 v;
  v[0] = (__bf16)a;
  v[1] = (__bf16)b;
  return __builtin_bit_cast(uint32_t, v);
}

// raw v_exp_f32 (exp2) — scores bounded (|s|<~10), no denormal concerns
__device__ __forceinline__ float EXP2(float x) { return __builtin_amdgcn_exp2f(x); }

// ---------------- fp32 -> bf16 convert (x) ----------------
__global__ void cvt_f32_bf16(const float* __restrict__ in, u16* __restrict__ out) {
  int i = (blockIdx.x * 256 + threadIdx.x) * 4;
  F128 v = *reinterpret_cast<const F128*>(in + i);
  U64v o;
  o.x = (uint32_t)f2bf(v.x) | ((uint32_t)f2bf(v.y) << 16);
  o.y = (uint32_t)f2bf(v.z) | ((uint32_t)f2bf(v.w) << 16);
  *reinterpret_cast<U64v*>(out + i) = o;
}

// ---------------- transpose + convert weights: W (K x N f32) -> Wt (N x K bf16) ----
__global__ void transpose_cvt(const float* __restrict__ W, u16* __restrict__ Wt,
                              int K, int N) {
  __shared__ float T[32][33];
  const int n0 = blockIdx.x * 32, k0 = blockIdx.y * 32;
  const int tid = threadIdx.x;
#pragma unroll
  for (int i = 0; i < 4; ++i) {
    int e = i * 256 + tid, r = e >> 5, c = e & 31;
    T[r][c] = W[(size_t)(k0 + r) * N + n0 + c];
  }
  __syncthreads();
#pragma unroll
  for (int i = 0; i < 4; ++i) {
    int e = i * 256 + tid, r = e >> 5, c = e & 31;
    Wt[(size_t)(n0 + r) * K + k0 + c] = f2bf(T[c][r]);
  }
}

// =====================================================================================
// 4-wave GEMM: BM=BN=128, BK=32, 3-slot cyclic LDS (48 KB -> 3 blocks/CU), counted
// vmcnt (loads of tile t+1 stay in flight across each barrier), XCD-swizzled grid.
// R7-measured: FETCH at swizzle-optimal, all pipes <30% -> latency-bound plateau
// (~73 us for qkv); kept as best-known GEMM structure for this shape.
// =====================================================================================

#define GEMM_PIPE(A_, Bt_, KD_, NKT_)                                                \
  const int tid = threadIdx.x;                                                       \
  const int wave = tid >> 6, lane = tid & 63;                                        \
  const int quad = lane >> 4, l16 = lane & 15;                                       \
  const int m0 = by * 128, n0 = bx * 128;                                            \
  const int wr = (wave & 1) * 64, wc = (wave >> 1) * 64;                             \
  f32x4 acc[4][4];                                                                   \
  _Pragma("unroll")                                                                  \
  for (int i = 0; i < 4; ++i)                                                        \
    _Pragma("unroll")                                                                \
    for (int j = 0; j < 4; ++j) acc[i][j] = (f32x4){0.f, 0.f, 0.f, 0.f};             \
  const int c0 = wave * 128 + lane;                                                  \
  const int row0 = c0 >> 2, kq0 = c0 & 3;                                            \
  const int c1 = c0 + 64;                                                            \
  const int row1 = c1 >> 2, kq1 = c1 & 3;                                            \
  const u16* Ag0 = (A_) + (size_t)(m0 + row0) * (KD_) + kq0 * 8;                     \
  const u16* Ag1 = (A_) + (size_t)(m0 + row1) * (KD_) + kq1 * 8;                     \
  const u16* Bg0 = (Bt_) + (size_t)(n0 + row0) * (KD_) + kq0 * 8;                    \
  const u16* Bg1 = (Bt_) + (size_t)(n0 + row1) * (KD_) + kq1 * 8;                    \
  STG(0, 0);                                                                         \
  STG(1, 1);                                                                         \
  for (int t = 0; t < (NKT_); ++t) {                                                 \
    __builtin_amdgcn_sched_barrier(0);                                               \
    if (t < (NKT_) - 1) asm volatile("s_waitcnt vmcnt(4)" ::: "memory");             \
    else                asm volatile("s_waitcnt vmcnt(0)" ::: "memory");             \
    __builtin_amdgcn_sched_barrier(0);                                               \
    __builtin_amdgcn_s_barrier();                                                    \
    __builtin_amdgcn_sched_barrier(0);                                               \
    if (t + 2 < (NKT_)) STG(t + 2, (t + 2) % 3);                                     \
    const u16* Ab = Asl + (t % 3) * 4096;                                            \
    const u16* Bb = Bsl + (t % 3) * 4096;                                            \
    bf16x8 af[4], bfr[4];                                                            \
    _Pragma("unroll")                                                                \
    for (int rb = 0; rb < 4; ++rb)                                                   \
      af[rb] = ldfrag(&Ab[(wr + rb * 16 + l16) * 32 + quad * 8]);                    \
    _Pragma("unroll")                                                                \
    for (int cb = 0; cb < 4; ++cb)                                                   \
      bfr[cb] = ldfrag(&Bb[(wc + cb * 16 + l16) * 32 + quad * 8]);                   \
    __builtin_amdgcn_s_setprio(1);                                                   \
    _Pragma("unroll")                                                                \
    for (int rb = 0; rb < 4; ++rb)                                                   \
      _Pragma("unroll")                                                              \
      for (int cb = 0; cb < 4; ++cb)                                                 \
        acc[rb][cb] = __builtin_amdgcn_mfma_f32_16x16x32_bf16(                       \
            af[rb], bfr[cb], acc[rb][cb], 0, 0, 0);                                  \
    __builtin_amdgcn_s_setprio(0);                                                   \
  }

#define STG(t_, s_)                                                                  \
  do {                                                                               \
    const int k0_ = (t_) * 32;                                                       \
    gld16(Ag0 + k0_, &Asl[(s_) * 4096 + wave * 1024]);                               \
    gld16(Bg0 + k0_, &Bsl[(s_) * 4096 + wave * 1024]);                               \
    gld16(Ag1 + k0_, &Asl[(s_) * 4096 + wave * 1024 + 512]);                         \
    gld16(Bg1 + k0_, &Bsl[(s_) * 4096 + wave * 1024 + 512]);                         \
  } while (0)

// ---------------- proj GEMM: C[M,N] = A[M,K] * Bt[N,K]^T + bias (f32 out) -----------
__global__ __launch_bounds__(256, 3)
void gemm_bt(const u16* __restrict__ A, const u16* __restrict__ Bt,
             const float* __restrict__ bias, float* __restrict__ C,
             int M, int N, int Karg) {
  (void)M; (void)Karg;
  __shared__ u16 Asl[3 * 4096];
  __shared__ u16 Bsl[3 * 4096];
  // XCD swizzle: grid (6,64) = 384 blocks, 48/XCD -> XCD c covers 8 A-panels
  const int orig = blockIdx.y * 6 + blockIdx.x;
  const int swz = (orig % 8) * 48 + orig / 8;
  const int bx = swz % 6, by = swz / 6;
  GEMM_PIPE(A, Bt, 768, 24)
#pragma unroll
  for (int cb = 0; cb < 4; ++cb) {
    int col = n0 + wc + cb * 16 + l16;
    float bv = bias[col];
#pragma unroll
    for (int rb = 0; rb < 4; ++rb) {
#pragma unroll
      for (int r = 0; r < 4; ++r) {
        int row = m0 + wr + rb * 16 + quad * 4 + r;
        C[(size_t)row * N + col] = acc[rb][cb][r] + bv;
      }
    }
  }
}

// ---------------- fused QKV GEMM + bias + RoPE + scatter ----------------------------
// Grid (18,64), XCD-swizzled. bx: 0-5 Q, 6-11 K, 12-17 V. Wave col-span 64 == one
// head. RoPE pair (d, d+32) lives in acc blocks (cb, cb+2) of the SAME lane.
// Q gets D^-0.5*log2e folded in (attn softmax runs in log2 domain).
// Q,K -> (B*H, N, D) bf16; V -> transposed (B*H, D, N) bf16 (4 tokens per 8B store).
__global__ __launch_bounds__(256, 3)
void gemm_qkv_rope(const u16* __restrict__ A, const u16* __restrict__ Bt,
                   const float* __restrict__ bias,
                   const float* __restrict__ cosT, const float* __restrict__ sinT,
                   const int* __restrict__ nsp,
                   u16* __restrict__ Qo, u16* __restrict__ Ko, u16* __restrict__ Vto) {
  __shared__ u16 Asl[3 * 4096];
  __shared__ u16 Bsl[3 * 4096];
  // XCD swizzle: grid (18,64) = 1152 blocks, 144/XCD -> XCD c covers 8 A-panels
  const int orig = blockIdx.y * 18 + blockIdx.x;
  const int swz = (orig % 8) * 144 + orig / 8;
  const int bx = swz % 18, by = swz / 18;
  GEMM_PIPE(A, Bt, 768, 24)

  // ---- fused epilogue ----
  const int sec = bx / 6;                  // 0=Q, 1=K, 2=V
  const int gcol0 = n0 + wc;               // 64-aligned: one head per wave
  const int hh = (gcol0 >> 6) % 12;
  const int bb = m0 >> 11;                 // 2048 % 128 == 0: one batch per block
  const int nbase = m0 & 2047;
  const int bh = bb * 12 + hh;
  const int num_special = nsp[0];
  const float QS = 0.125f * 1.4426950408889634f;  // D^-0.5 * log2e

  if (sec < 2) {
    u16* outp = sec ? Ko : Qo;
    const float qs = sec ? 1.0f : QS;
#pragma unroll
    for (int cbp = 0; cbp < 2; ++cbp) {
      const int d1 = cbp * 16 + l16;       // 0..31
      const int d2 = d1 + 32;
      const float bv1 = bias[gcol0 + d1];
      const float bv2 = bias[gcol0 + d2];
#pragma unroll
      for (int rb = 0; rb < 4; ++rb) {
#pragma unroll
        for (int r = 0; r < 4; ++r) {
          const int n = nbase + wr + rb * 16 + quad * 4 + r;
          float v1 = acc[rb][cbp][r] + bv1;
          float v2 = acc[rb][cbp + 2][r] + bv2;
          float o1, o2;
          if (n < num_special) {
            o1 = v1; o2 = v2;
          } else {
            int ns = n - num_special;
            float c1 = cosT[ns * 64 + d1], s1 = sinT[ns * 64 + d1];
            float c2 = cosT[ns * 64 + d2], s2 = sinT[ns * 64 + d2];
            o1 = v1 * c1 - v2 * s1;
            o2 = v2 * c2 + v1 * s2;
          }
          size_t ob = ((size_t)bh * 2048 + n) * 64;
          outp[ob + d1] = f2bf(o1 * qs);
          outp[ob + d2] = f2bf(o2 * qs);
        }
      }
    }
  } else {
    // V: bias + transposed write (d-major), 4 consecutive tokens per 8B store
#pragma unroll
    for (int cb = 0; cb < 4; ++cb) {
      const int d = cb * 16 + l16;
      const float bv = bias[gcol0 + d];
#pragma unroll
      for (int rb = 0; rb < 4; ++rb) {
        const int nr = nbase + wr + rb * 16 + quad * 4;
        U64v o;
        o.x = (uint32_t)f2bf(acc[rb][cb][0] + bv) |
              ((uint32_t)f2bf(acc[rb][cb][1] + bv) << 16);
        o.y = (uint32_t)f2bf(acc[rb][cb][2] + bv) |
              ((uint32_t)f2bf(acc[rb][cb][3] + bv) << 16);
        *(U64v*)&Vto[((size_t)bh * 64 + d) * 2048 + nr] = o;
      }
    }
  }
}

// ---------------- flash attention: wave-owns-keys, pair-PV at K=32 -----------------
// Single launch, grid 1536 = qt*48 + bh (2 residency rounds at 3 blocks/CU).
// 4 waves; wave owns keys [wave*16, wave*16+16) of each 64-key tile. Q hoisted to
// registers. K/V staged via global_load_lds width-16 (linear dest + XOR swizzle),
// 2-slot double buffer, 1 sync/tile (R5-proven cadence).
// NEW: P is accumulated over TWO key-tiles (even/odd), then ONE PV per pair using
// mfma_f32_16x16x32_bf16 with A = concat(pfE, pfO), B = concat(vE, vO). The MFMA
// k-index is a free bijection: position k = quad*8 + tile*4 + r maps to
// (tile, local key quad*4+r) identically on both operands -> no shuffles, C/D
// layout unchanged. MFMA slots per pair: 48 -> 32 (PV at full K=32 rate).
// S^T = MFMA(A=K_own, B=Q); exp'd values feed PV A directly. No-max softmax.
__global__ __launch_bounds__(256, 3)
void attn(const u16* __restrict__ Q, const u16* __restrict__ Kg,
          const u16* __restrict__ Vt, u16* __restrict__ Out) {
  __shared__ u16 smem2[2 * 8192];    // 32 KB: [slot][K 64x64 | V 64x64]; epilogue overlays
  __shared__ float invS[64];
  const int tid = threadIdx.x;
  const int wave = tid >> 6, lane = tid & 63;
  const int quad = lane >> 4, l16 = lane & 15;
  const int idx = blockIdx.x;
  const int bh = idx % 48, qt = idx / 48;
  const int b = bh / 12, h = bh % 12;
  const u16* Qb = Q + (size_t)bh * 2048 * 64;
  const u16* Kb = Kg + (size_t)bh * 2048 * 64;
  const u16* Vb = Vt + (size_t)bh * 64 * 2048;
  const int wkey0 = wave * 16;

  // ---- staging geometry (loop-invariant) ----
  const int lrow = lane >> 3;                 // 0..7 within an 8-row call region
  const int lch  = (lane & 7) ^ (lrow & 7);   // pre-swizzled source 16B-chunk
  const int r0a = wave * 8;                   // call 0 rows
  const int r0b = 32 + wave * 8;              // call 1 rows
  const int ksrc_a = (r0a + lrow) * 64 + lch * 8;   // u16 offsets into a [64][64] K tile
  const int ksrc_b = (r0b + lrow) * 64 + lch * 8;
  const size_t vsrc_a = (size_t)(r0a + lrow) * 2048 + lch * 8;  // V rows are d-rows
  const size_t vsrc_b = (size_t)(r0b + lrow) * 2048 + lch * 8;

  // ---- LDS read offsets (swizzled, loop-invariant) ----
  const int krd = (wkey0 + l16) * 64 + ((quad ^ (l16 & 7)) << 3);     // ka0; ka1 = ^32
  int vrd[4];
#pragma unroll
  for (int db = 0; db < 4; ++db)
    vrd[db] = (db * 16 + l16) * 64 +
              ((((wave << 1) | (quad >> 1)) ^ (l16 & 7)) << 3) + (quad & 1) * 4;

#define STAGE_A(kt_, s_)                                                      \
  do {                                                                        \
    u16* Kd = smem2 + (s_) * 8192;                                            \
    u16* Vd = Kd + 4096;                                                      \
    const u16* Ksrc = Kb + (size_t)(kt_) * 4096;                              \
    const u16* Vsrc = Vb + (kt_) * 64;                                        \
    gld16(Ksrc + ksrc_a, Kd + r0a * 64);                                      \
    gld16(Ksrc + ksrc_b, Kd + r0b * 64);                                      \
    gld16(Vsrc + vsrc_a, Vd + r0a * 64);                                      \
    gld16(Vsrc + vsrc_b, Vd + r0b * 64);                                      \
  } while (0)

// QK of one tile from LDS slot base Ksh_/Vsh_ -> pf_[4] (U64v) and vdst_[4]
#define QK_TILE(Ksh_, Vsh_, pf_, vdst_)                                       \
  do {                                                                        \
    bf16x8 ka0_ = ldfrag((Ksh_) + krd);                                       \
    bf16x8 ka1_ = ldfrag((Ksh_) + (krd ^ 32));                                \
    _Pragma("unroll")                                                         \
    for (int db = 0; db < 4; ++db)                                            \
      (vdst_)[db] = *(const U64v*)((Vsh_) + vrd[db]);                         \
    _Pragma("unroll")                                                         \
    for (int m = 0; m < 4; ++m) {                                             \
      f32x4 st = (f32x4){0.f, 0.f, 0.f, 0.f};                                 \
      st = __builtin_amdgcn_mfma_f32_16x16x32_bf16(ka0_, qf[m][0], st, 0, 0, 0); \
      st = __builtin_amdgcn_mfma_f32_16x16x32_bf16(ka1_, qf[m][1], st, 0, 0, 0); \
      float p0 = EXP2(st[0]), p1 = EXP2(st[1]), p2 = EXP2(st[2]), p3 = EXP2(st[3]); \
      psum[m] += (p0 + p1) + (p2 + p3);                                       \
      U64v pd_; pd_.x = pkbf(p0, p1); pd_.y = pkbf(p2, p3);                   \
      (pf_)[m] = pd_;                                                         \
    }                                                                         \
  } while (0)

  // Q fragments: direct global load (one-time; reused 32x)
  bf16x8 qf[4][2];
#pragma unroll
  for (int m = 0; m < 4; ++m) {
    const u16* qp = Qb + (size_t)(qt * 64 + m * 16 + l16) * 64 + quad * 8;
    qf[m][0] = ldfrag(qp);
    qf[m][1] = ldfrag(qp + 32);
  }

  f32x4 oacc[4][4];  // [q-block m][d-block db], partial over this wave's keys
#pragma unroll
  for (int m = 0; m < 4; ++m)
#pragma unroll
    for (int db = 0; db < 4; ++db) oacc[m][db] = (f32x4){0.f, 0.f, 0.f, 0.f};
  float psum[4] = {0.f, 0.f, 0.f, 0.f};

  U64v pfE[4], pfO[4], vE[4], vO[4];

  // ---- prologue: stage tiles 0,1; QK(0) -> pfE,vE ----
  STAGE_A(0, 0);
  STAGE_A(1, 1);
  __syncthreads();
  QK_TILE(smem2, smem2 + 4096, pfE, vE);
  __syncthreads();                        // all waves done with slot 0 reads

  // ---- 15 pair-iterations: tiles {2j,2j+1} PV'd in body(2j+1) ----
  for (int j = 0; j < 15; ++j) {
    // body kt=2j: read tile 2j+1 (slot 1), stage tile 2j+2 -> slot 0, QK -> pfO,vO
    {
      const u16* Ksh = smem2 + 8192;
      STAGE_A(2 * j + 2, 0);
      QK_TILE(Ksh, Ksh + 4096, pfO, vO);
      __syncthreads();
    }
    // body kt=2j+1: read tile 2j+2 (slot 0), stage tile 2j+3 -> slot 1,
    //               QK -> pfN,vN; PV(pair j) at K=32; shift E <- N
    {
      const u16* Ksh = smem2;
      U64v pfN[4], vN[4];
      STAGE_A(2 * j + 3, 1);
      QK_TILE(Ksh, Ksh + 4096, pfN, vN);
      // PV: one K=32 MFMA per (m, db) covering both tiles' 32 keys
#pragma unroll
      for (int db = 0; db < 4; ++db) {
        bf16x8 vf8 = cat8(vE[db], vO[db]);
#pragma unroll
        for (int m = 0; m < 4; ++m)
          oacc[m][db] = __builtin_amdgcn_mfma_f32_16x16x32_bf16(
              cat8(pfE[m], pfO[m]), vf8, oacc[m][db], 0, 0, 0);
      }
      __syncthreads();
#pragma unroll
      for (int m = 0; m < 4; ++m) pfE[m] = pfN[m];
#pragma unroll
      for (int db = 0; db < 4; ++db) vE[db] = vN[db];
    }
  }

  // ---- final body kt=30: read tile 31 (slot 1), QK -> pfO,vO (no stage) ----
  {
    const u16* Ksh = smem2 + 8192;
    QK_TILE(Ksh, Ksh + 4096, pfO, vO);
  }
  // ---- drain: PV(pair 15) ----
#pragma unroll
  for (int db = 0; db < 4; ++db) {
    bf16x8 vf8 = cat8(vE[db], vO[db]);
#pragma unroll
    for (int m = 0; m < 4; ++m)
      oacc[m][db] = __builtin_amdgcn_mfma_f32_16x16x32_bf16(
          cat8(pfE[m], pfO[m]), vf8, oacc[m][db], 0, 0, 0);
  }
#undef STAGE_A
#undef QK_TILE

  // ---- epilogue: cross-wave reductions ----
#pragma unroll
  for (int m = 0; m < 4; ++m) {
    psum[m] += __shfl_xor(psum[m], 16, 64);
    psum[m] += __shfl_xor(psum[m], 32, 64);
  }
  __syncthreads();
  float* LS = (float*)smem2;       // [wave][64 q]
  if (quad == 0) {
#pragma unroll
    for (int m = 0; m < 4; ++m) LS[wave * 64 + m * 16 + l16] = psum[m];
  }
  __syncthreads();
  if (tid < 64) {
    float tot = LS[tid] + LS[64 + tid] + LS[128 + tid] + LS[192 + tid];
    invS[tid] = 1.0f / tot;
  }

  float* OR = (float*)smem2;       // 4*64*18*4 B = 18432 B < 32 KB
  const int q = tid >> 2;
  const int d0 = (tid & 3) * 4;
  const size_t obase = ((size_t)(b * 2048 + qt * 64 + q)) * 768 + h * 64 + d0;
#pragma unroll
  for (int db = 0; db < 4; ++db) {
    __syncthreads();
#pragma unroll
    for (int m = 0; m < 4; ++m)
#pragma unroll
      for (int r = 0; r < 4; ++r)
        OR[(wave * 64 + m * 16 + quad * 4 + r) * 18 + l16] = oacc[m][db][r];
    __syncthreads();
    float s0 = 0.f, s1 = 0.f, s2 = 0.f, s3 = 0.f;
#pragma unroll
    for (int w = 0; w < 4; ++w) {
      const float* p = &OR[(w * 64 + q) * 18 + d0];
      s0 += p[0]; s1 += p[1]; s2 += p[2]; s3 += p[3];
    }
    float iv = invS[q];
    U64v o;
    o.x = (uint32_t)f2bf(s0 * iv) | ((uint32_t)f2bf(s1 * iv) << 16);
    o.y = (uint32_t)f2bf(s2 * iv) | ((uint32_t)f2bf(s3 * iv) << 16);
    *(U64v*)&Out[obase + db * 16] = o;
  }
}

extern "C" void kernel_launch(void* const* d_in, const int* in_sizes, int n_in,
                              void* d_out, int out_size, void* d_ws, size_t ws_size,
                              hipStream_t stream) {
  (void)in_sizes; (void)n_in; (void)out_size; (void)ws_size;
  const float* x        = (const float*)d_in[0];
  const float* rope_cos = (const float*)d_in[1];
  const float* rope_sin = (const float*)d_in[2];
  const float* W_qkv    = (const float*)d_in[3];
  const float* b_qkv    = (const float*)d_in[4];
  const float* W_proj   = (const float*)d_in[5];
  const float* b_proj   = (const float*)d_in[6];
  const int*   nsp      = (const int*)d_in[7];
  float* out = (float*)d_out;

  char* ws = (char*)d_ws;
  u16* Xb   = (u16*)(ws);              // 8192x768 bf16
  u16* Wqkt = (u16*)(ws + 12582912);   // 2304x768 bf16
  u16* Wpt  = (u16*)(ws + 16121856);   // 768x768 bf16
  u16* Qb   = (u16*)(ws + 55050240);   // 48x2048x64 bf16
  u16* Kb   = (u16*)(ws + 67633152);
  u16* Vtb  = (u16*)(ws + 80216064);   // 48x64x2048 bf16
  u16* att  = (u16*)(ws + 92798976);   // 8192x768 bf16

  cvt_f32_bf16<<<6144, 256, 0, stream>>>(x, Xb);
  transpose_cvt<<<dim3(72, 24), 256, 0, stream>>>(W_qkv, Wqkt, 768, 2304);
  transpose_cvt<<<dim3(24, 24), 256, 0, stream>>>(W_proj, Wpt, 768, 768);
  gemm_qkv_rope<<<dim3(18, 64), 256, 0, stream>>>(Xb, Wqkt, b_qkv, rope_cos, rope_sin,
                                                  nsp, Qb, Kb, Vtb);
  attn<<<1536, 256, 0, stream>>>(Qb, Kb, Vtb, att);
  gemm_bt<<<dim3(6, 64), 256, 0, stream>>>(att, Wpt, b_proj, out, 8192, 768, 768);
}

// Round 9
// 337.973 us; speedup vs baseline: 1.0892x; 1.0892x over previous
//
#include <hip/hip_runtime.h>
#include <stdint.h>

typedef unsigned short u16;
typedef __bf16 bf16x8 __attribute__((ext_vector_type(8)));
typedef __bf16 bf16x2 __attribute__((ext_vector_type(2)));
typedef short s16x4 __attribute__((ext_vector_type(4)));
typedef float f32x4 __attribute__((ext_vector_type(4)));

typedef __attribute__((address_space(1))) void gvoid_t;
typedef __attribute__((address_space(3))) void lvoid_t;

struct alignas(16) U128 { uint32_t x, y, z, w; };
struct alignas(16) F128 { float x, y, z, w; };
struct alignas(8)  U64v { uint32_t x, y; };

__device__ __forceinline__ void gld16(const u16* g, u16* lds) {
  __builtin_amdgcn_global_load_lds((gvoid_t*)const_cast<u16*>(g),
                                   (lvoid_t*)lds, 16, 0, 0);
}

__device__ __forceinline__ u16 f2bf(float f) {
  uint32_t u = __builtin_bit_cast(uint32_t, f);
  u += 0x7FFFu + ((u >> 16) & 1u);   // RNE
  return (u16)(u >> 16);
}
__device__ __forceinline__ float bf2f(u16 h) {
  return __builtin_bit_cast(float, (uint32_t)h << 16);
}
__device__ __forceinline__ bf16x8 ldfrag(const u16* p) {
  U128 u = *reinterpret_cast<const U128*>(p);
  return __builtin_bit_cast(bf16x8, u);
}
// concat two 4x-bf16 halves into one 8x-bf16 MFMA fragment (no shuffles)
__device__ __forceinline__ bf16x8 cat8(U64v lo, U64v hi) {
  U128 u; u.x = lo.x; u.y = lo.y; u.z = hi.x; u.w = hi.y;
  return __builtin_bit_cast(bf16x8, u);
}
// pack two f32 -> bf16x2 dword via HW cvt (compiler emits v_cvt_pk_bf16_f32)
__device__ __forceinline__ uint32_t pkbf(float a, float b) {
  bf16x2 v;
  v[0] = (__bf16)a;
  v[1] = (__bf16)b;
  return __builtin_bit_cast(uint32_t, v);
}

// raw v_exp_f32 (exp2) — scores bounded (|s|<~10), no denormal concerns
__device__ __forceinline__ float EXP2(float x) { return __builtin_amdgcn_exp2f(x); }

// ---------------- fused prep: fp32->bf16 convert (x) + both weight transposes -------
// Grid 8448: [0,6144) cvt x; [6144,7872) transpose W_qkv (72x24); [7872,8448)
// transpose W_proj (24x24). One launch instead of three (cuts dispatch overhead).
__global__ void prep(const float* __restrict__ x, u16* __restrict__ Xb,
                     const float* __restrict__ Wq, u16* __restrict__ Wqkt,
                     const float* __restrict__ Wp, u16* __restrict__ Wpt) {
  const int id = blockIdx.x;
  const int tid = threadIdx.x;
  if (id < 6144) {
    int i = (id * 256 + tid) * 4;
    F128 v = *reinterpret_cast<const F128*>(x + i);
    U64v o;
    o.x = (uint32_t)f2bf(v.x) | ((uint32_t)f2bf(v.y) << 16);
    o.y = (uint32_t)f2bf(v.z) | ((uint32_t)f2bf(v.w) << 16);
    *reinterpret_cast<U64v*>(Xb + i) = o;
    return;
  }
  __shared__ float T[32][33];
  const float* W; u16* Wt; int K, N, n0, k0;
  if (id < 7872) {
    int e = id - 6144; W = Wq; Wt = Wqkt; K = 768; N = 2304;
    n0 = (e % 72) * 32; k0 = (e / 72) * 32;
  } else {
    int e = id - 7872; W = Wp; Wt = Wpt; K = 768; N = 768;
    n0 = (e % 24) * 32; k0 = (e / 24) * 32;
  }
#pragma unroll
  for (int i = 0; i < 4; ++i) {
    int e = i * 256 + tid, r = e >> 5, c = e & 31;
    T[r][c] = W[(size_t)(k0 + r) * N + n0 + c];
  }
  __syncthreads();
#pragma unroll
  for (int i = 0; i < 4; ++i) {
    int e = i * 256 + tid, r = e >> 5, c = e & 31;
    Wt[(size_t)(n0 + r) * K + k0 + c] = f2bf(T[c][r]);
  }
}

// =====================================================================================
// 4-wave GEMM: BM=BN=128, BK=32, 3-slot cyclic LDS (48 KB -> 3 blocks/CU), counted
// vmcnt (loads of tile t+1 stay in flight across each barrier), XCD-swizzled grid.
// R7-measured: FETCH at swizzle-optimal; latency-bound plateau ~73 us (qkv); kept as
// best-known GEMM structure for this shape.
// =====================================================================================

#define GEMM_PIPE(A_, Bt_, KD_, NKT_)                                                \
  const int tid = threadIdx.x;                                                       \
  const int wave = tid >> 6, lane = tid & 63;                                        \
  const int quad = lane >> 4, l16 = lane & 15;                                       \
  const int m0 = by * 128, n0 = bx * 128;                                            \
  const int wr = (wave & 1) * 64, wc = (wave >> 1) * 64;                             \
  f32x4 acc[4][4];                                                                   \
  _Pragma("unroll")                                                                  \
  for (int i = 0; i < 4; ++i)                                                        \
    _Pragma("unroll")                                                                \
    for (int j = 0; j < 4; ++j) acc[i][j] = (f32x4){0.f, 0.f, 0.f, 0.f};             \
  const int c0 = wave * 128 + lane;                                                  \
  const int row0 = c0 >> 2, kq0 = c0 & 3;                                            \
  const int c1 = c0 + 64;                                                            \
  const int row1 = c1 >> 2, kq1 = c1 & 3;                                            \
  const u16* Ag0 = (A_) + (size_t)(m0 + row0) * (KD_) + kq0 * 8;                     \
  const u16* Ag1 = (A_) + (size_t)(m0 + row1) * (KD_) + kq1 * 8;                     \
  const u16* Bg0 = (Bt_) + (size_t)(n0 + row0) * (KD_) + kq0 * 8;                    \
  const u16* Bg1 = (Bt_) + (size_t)(n0 + row1) * (KD_) + kq1 * 8;                    \
  STG(0, 0);                                                                         \
  STG(1, 1);                                                                         \
  for (int t = 0; t < (NKT_); ++t) {                                                 \
    __builtin_amdgcn_sched_barrier(0);                                               \
    if (t < (NKT_) - 1) asm volatile("s_waitcnt vmcnt(4)" ::: "memory");             \
    else                asm volatile("s_waitcnt vmcnt(0)" ::: "memory");             \
    __builtin_amdgcn_sched_barrier(0);                                               \
    __builtin_amdgcn_s_barrier();                                                    \
    __builtin_amdgcn_sched_barrier(0);                                               \
    if (t + 2 < (NKT_)) STG(t + 2, (t + 2) % 3);                                     \
    const u16* Ab = Asl + (t % 3) * 4096;                                            \
    const u16* Bb = Bsl + (t % 3) * 4096;                                            \
    bf16x8 af[4], bfr[4];                                                            \
    _Pragma("unroll")                                                                \
    for (int rb = 0; rb < 4; ++rb)                                                   \
      af[rb] = ldfrag(&Ab[(wr + rb * 16 + l16) * 32 + quad * 8]);                    \
    _Pragma("unroll")                                                                \
    for (int cb = 0; cb < 4; ++cb)                                                   \
      bfr[cb] = ldfrag(&Bb[(wc + cb * 16 + l16) * 32 + quad * 8]);                   \
    __builtin_amdgcn_s_setprio(1);                                                   \
    _Pragma("unroll")                                                                \
    for (int rb = 0; rb < 4; ++rb)                                                   \
      _Pragma("unroll")                                                              \
      for (int cb = 0; cb < 4; ++cb)                                                 \
        acc[rb][cb] = __builtin_amdgcn_mfma_f32_16x16x32_bf16(                       \
            af[rb], bfr[cb], acc[rb][cb], 0, 0, 0);                                  \
    __builtin_amdgcn_s_setprio(0);                                                   \
  }

#define STG(t_, s_)                                                                  \
  do {                                                                               \
    const int k0_ = (t_) * 32;                                                       \
    gld16(Ag0 + k0_, &Asl[(s_) * 4096 + wave * 1024]);                               \
    gld16(Bg0 + k0_, &Bsl[(s_) * 4096 + wave * 1024]);                               \
    gld16(Ag1 + k0_, &Asl[(s_) * 4096 + wave * 1024 + 512]);                         \
    gld16(Bg1 + k0_, &Bsl[(s_) * 4096 + wave * 1024 + 512]);                         \
  } while (0)

// ---------------- proj GEMM: C[M,N] = A[M,K] * Bt[N,K]^T + bias (f32 out) -----------
__global__ __launch_bounds__(256, 3)
void gemm_bt(const u16* __restrict__ A, const u16* __restrict__ Bt,
             const float* __restrict__ bias, float* __restrict__ C,
             int M, int N, int Karg) {
  (void)M; (void)Karg;
  __shared__ u16 Asl[3 * 4096];
  __shared__ u16 Bsl[3 * 4096];
  const int orig = blockIdx.y * 6 + blockIdx.x;
  const int swz = (orig % 8) * 48 + orig / 8;
  const int bx = swz % 6, by = swz / 6;
  GEMM_PIPE(A, Bt, 768, 24)
#pragma unroll
  for (int cb = 0; cb < 4; ++cb) {
    int col = n0 + wc + cb * 16 + l16;
    float bv = bias[col];
#pragma unroll
    for (int rb = 0; rb < 4; ++rb) {
#pragma unroll
      for (int r = 0; r < 4; ++r) {
        int row = m0 + wr + rb * 16 + quad * 4 + r;
        C[(size_t)row * N + col] = acc[rb][cb][r] + bv;
      }
    }
  }
}

// ---------------- fused QKV GEMM + bias + RoPE + scatter ----------------------------
__global__ __launch_bounds__(256, 3)
void gemm_qkv_rope(const u16* __restrict__ A, const u16* __restrict__ Bt,
                   const float* __restrict__ bias,
                   const float* __restrict__ cosT, const float* __restrict__ sinT,
                   const int* __restrict__ nsp,
                   u16* __restrict__ Qo, u16* __restrict__ Ko, u16* __restrict__ Vto) {
  __shared__ u16 Asl[3 * 4096];
  __shared__ u16 Bsl[3 * 4096];
  const int orig = blockIdx.y * 18 + blockIdx.x;
  const int swz = (orig % 8) * 144 + orig / 8;
  const int bx = swz % 18, by = swz / 18;
  GEMM_PIPE(A, Bt, 768, 24)

  const int sec = bx / 6;                  // 0=Q, 1=K, 2=V
  const int gcol0 = n0 + wc;               // 64-aligned: one head per wave
  const int hh = (gcol0 >> 6) % 12;
  const int bb = m0 >> 11;
  const int nbase = m0 & 2047;
  const int bh = bb * 12 + hh;
  const int num_special = nsp[0];
  const float QS = 0.125f * 1.4426950408889634f;  // D^-0.5 * log2e

  if (sec < 2) {
    u16* outp = sec ? Ko : Qo;
    const float qs = sec ? 1.0f : QS;
#pragma unroll
    for (int cbp = 0; cbp < 2; ++cbp) {
      const int d1 = cbp * 16 + l16;
      const int d2 = d1 + 32;
      const float bv1 = bias[gcol0 + d1];
      const float bv2 = bias[gcol0 + d2];
#pragma unroll
      for (int rb = 0; rb < 4; ++rb) {
#pragma unroll
        for (int r = 0; r < 4; ++r) {
          const int n = nbase + wr + rb * 16 + quad * 4 + r;
          float v1 = acc[rb][cbp][r] + bv1;
          float v2 = acc[rb][cbp + 2][r] + bv2;
          float o1, o2;
          if (n < num_special) {
            o1 = v1; o2 = v2;
          } else {
            int ns = n - num_special;
            float c1 = cosT[ns * 64 + d1], s1 = sinT[ns * 64 + d1];
            float c2 = cosT[ns * 64 + d2], s2 = sinT[ns * 64 + d2];
            o1 = v1 * c1 - v2 * s1;
            o2 = v2 * c2 + v1 * s2;
          }
          size_t ob = ((size_t)bh * 2048 + n) * 64;
          outp[ob + d1] = f2bf(o1 * qs);
          outp[ob + d2] = f2bf(o2 * qs);
        }
      }
    }
  } else {
#pragma unroll
    for (int cb = 0; cb < 4; ++cb) {
      const int d = cb * 16 + l16;
      const float bv = bias[gcol0 + d];
#pragma unroll
      for (int rb = 0; rb < 4; ++rb) {
        const int nr = nbase + wr + rb * 16 + quad * 4;
        U64v o;
        o.x = (uint32_t)f2bf(acc[rb][cb][0] + bv) |
              ((uint32_t)f2bf(acc[rb][cb][1] + bv) << 16);
        o.y = (uint32_t)f2bf(acc[rb][cb][2] + bv) |
              ((uint32_t)f2bf(acc[rb][cb][3] + bv) << 16);
        *(U64v*)&Vto[((size_t)bh * 64 + d) * 2048 + nr] = o;
      }
    }
  }
}

// ---------------- flash attention: wave-owns-keys, pair-PV at K=32, low-state ------
// Single launch, grid 1536 = qt*48 + bh. Pair j = tiles {2j, 2j+1}:
//   body-even (tile 2j, slot0):  QK -> pfE,vE; sync.          [slot0 readers done]
//   body-odd  (tile 2j+1, slot1): STAGE(2j+2 -> slot0); QK -> pfO,vO;
//                                 PV(pfE||pfO, vE||vO) @K=32; sync;
//                                 STAGE(2j+3 -> slot1).       [drained next sync]
// Live across barriers: pfE/vE only (16 VGPR) -> under the 168 cap (R8's 3-deep
// state spilled ~150 MB/dispatch). MFMA slots/pair: 16 QK + 16 PV = 32 (was 48).
// k-position quad*8 + tile*4 + r used identically on A and B -> exact math.
__global__ __launch_bounds__(256, 3)
void attn(const u16* __restrict__ Q, const u16* __restrict__ Kg,
          const u16* __restrict__ Vt, u16* __restrict__ Out) {
  __shared__ u16 smem2[2 * 8192];    // 32 KB: [slot][K 64x64 | V 64x64]; epilogue overlays
  __shared__ float invS[64];
  const int tid = threadIdx.x;
  const int wave = tid >> 6, lane = tid & 63;
  const int quad = lane >> 4, l16 = lane & 15;
  const int idx = blockIdx.x;
  const int bh = idx % 48, qt = idx / 48;
  const int b = bh / 12, h = bh % 12;
  const u16* Qb = Q + (size_t)bh * 2048 * 64;
  const u16* Kb = Kg + (size_t)bh * 2048 * 64;
  const u16* Vb = Vt + (size_t)bh * 64 * 2048;
  const int wkey0 = wave * 16;

  const int lrow = lane >> 3;
  const int lch  = (lane & 7) ^ (lrow & 7);
  const int r0a = wave * 8;
  const int r0b = 32 + wave * 8;
  const int ksrc_a = (r0a + lrow) * 64 + lch * 8;
  const int ksrc_b = (r0b + lrow) * 64 + lch * 8;
  const size_t vsrc_a = (size_t)(r0a + lrow) * 2048 + lch * 8;
  const size_t vsrc_b = (size_t)(r0b + lrow) * 2048 + lch * 8;

  const int krd = (wkey0 + l16) * 64 + ((quad ^ (l16 & 7)) << 3);
  int vrd[4];
#pragma unroll
  for (int db = 0; db < 4; ++db)
    vrd[db] = (db * 16 + l16) * 64 +
              ((((wave << 1) | (quad >> 1)) ^ (l16 & 7)) << 3) + (quad & 1) * 4;

#define STAGE_A(kt_, s_)                                                      \
  do {                                                                        \
    u16* Kd = smem2 + (s_) * 8192;                                            \
    u16* Vd = Kd + 4096;                                                      \
    const u16* Ksrc = Kb + (size_t)(kt_) * 4096;                              \
    const u16* Vsrc = Vb + (kt_) * 64;                                        \
    gld16(Ksrc + ksrc_a, Kd + r0a * 64);                                      \
    gld16(Ksrc + ksrc_b, Kd + r0b * 64);                                      \
    gld16(Vsrc + vsrc_a, Vd + r0a * 64);                                      \
    gld16(Vsrc + vsrc_b, Vd + r0b * 64);                                      \
  } while (0)

#define QK_TILE(Ksh_, Vsh_, pf_, vdst_)                                       \
  do {                                                                        \
    bf16x8 ka0_ = ldfrag((Ksh_) + krd);                                       \
    bf16x8 ka1_ = ldfrag((Ksh_) + (krd ^ 32));                                \
    _Pragma("unroll")                                                         \
    for (int db = 0; db < 4; ++db)                                            \
      (vdst_)[db] = *(const U64v*)((Vsh_) + vrd[db]);                         \
    _Pragma("unroll")                                                         \
    for (int m = 0; m < 4; ++m) {                                             \
      f32x4 st = (f32x4){0.f, 0.f, 0.f, 0.f};                                 \
      st = __builtin_amdgcn_mfma_f32_16x16x32_bf16(ka0_, qf[m][0], st, 0, 0, 0); \
      st = __builtin_amdgcn_mfma_f32_16x16x32_bf16(ka1_, qf[m][1], st, 0, 0, 0); \
      float p0 = EXP2(st[0]), p1 = EXP2(st[1]), p2 = EXP2(st[2]), p3 = EXP2(st[3]); \
      psum[m] += (p0 + p1) + (p2 + p3);                                       \
      U64v pd_; pd_.x = pkbf(p0, p1); pd_.y = pkbf(p2, p3);                   \
      (pf_)[m] = pd_;                                                         \
    }                                                                         \
  } while (0)

  bf16x8 qf[4][2];
#pragma unroll
  for (int m = 0; m < 4; ++m) {
    const u16* qp = Qb + (size_t)(qt * 64 + m * 16 + l16) * 64 + quad * 8;
    qf[m][0] = ldfrag(qp);
    qf[m][1] = ldfrag(qp + 32);
  }

  f32x4 oacc[4][4];
#pragma unroll
  for (int m = 0; m < 4; ++m)
#pragma unroll
    for (int db = 0; db < 4; ++db) oacc[m][db] = (f32x4){0.f, 0.f, 0.f, 0.f};
  float psum[4] = {0.f, 0.f, 0.f, 0.f};

  U64v pfE[4], pfO[4], vE[4], vO[4];

  STAGE_A(0, 0);
  STAGE_A(1, 1);
  __syncthreads();

  for (int j = 0; j < 16; ++j) {
    // body-even: tile 2j in slot0 (no staging; slot1 untouched, slot0 being read)
    QK_TILE(smem2, smem2 + 4096, pfE, vE);
    __syncthreads();                      // slot0 readers done; drains prior stage
    // body-odd: tile 2j+1 in slot1; stage 2j+2 -> slot0; PV of the pair
    if (j < 15) STAGE_A(2 * j + 2, 0);
    QK_TILE(smem2 + 8192, smem2 + 8192 + 4096, pfO, vO);
#pragma unroll
    for (int db = 0; db < 4; ++db) {
      bf16x8 vf8 = cat8(vE[db], vO[db]);
#pragma unroll
      for (int m = 0; m < 4; ++m)
        oacc[m][db] = __builtin_amdgcn_mfma_f32_16x16x32_bf16(
            cat8(pfE[m], pfO[m]), vf8, oacc[m][db], 0, 0, 0);
    }
    __syncthreads();                      // slot1 readers done; drains slot0 stage
    if (j < 15) STAGE_A(2 * j + 3, 1);    // drained by next body-even's sync
  }
#undef STAGE_A
#undef QK_TILE

#pragma unroll
  for (int m = 0; m < 4; ++m) {
    psum[m] += __shfl_xor(psum[m], 16, 64);
    psum[m] += __shfl_xor(psum[m], 32, 64);
  }
  __syncthreads();
  float* LS = (float*)smem2;
  if (quad == 0) {
#pragma unroll
    for (int m = 0; m < 4; ++m) LS[wave * 64 + m * 16 + l16] = psum[m];
  }
  __syncthreads();
  if (tid < 64) {
    float tot = LS[tid] + LS[64 + tid] + LS[128 + tid] + LS[192 + tid];
    invS[tid] = 1.0f / tot;
  }

  float* OR = (float*)smem2;
  const int q = tid >> 2;
  const int d0 = (tid & 3) * 4;
  const size_t obase = ((size_t)(b * 2048 + qt * 64 + q)) * 768 + h * 64 + d0;
#pragma unroll
  for (int db = 0; db < 4; ++db) {
    __syncthreads();
#pragma unroll
    for (int m = 0; m < 4; ++m)
#pragma unroll
      for (int r = 0; r < 4; ++r)
        OR[(wave * 64 + m * 16 + quad * 4 + r) * 18 + l16] = oacc[m][db][r];
    __syncthreads();
    float s0 = 0.f, s1 = 0.f, s2 = 0.f, s3 = 0.f;
#pragma unroll
    for (int w = 0; w < 4; ++w) {
      const float* p = &OR[(w * 64 + q) * 18 + d0];
      s0 += p[0]; s1 += p[1]; s2 += p[2]; s3 += p[3];
    }
    float iv = invS[q];
    U64v o;
    o.x = (uint32_t)f2bf(s0 * iv) | ((uint32_t)f2bf(s1 * iv) << 16);
    o.y = (uint32_t)f2bf(s2 * iv) | ((uint32_t)f2bf(s3 * iv) << 16);
    *(U64v*)&Out[obase + db * 16] = o;
  }
}

extern "C" void kernel_launch(void* const* d_in, const int* in_sizes, int n_in,
                              void* d_out, int out_size, void* d_ws, size_t ws_size,
                              hipStream_t stream) {
  (void)in_sizes; (void)n_in; (void)out_size; (void)ws_size;
  const float* x        = (const float*)d_in[0];
  const float* rope_cos = (const float*)d_in[1];
  const float* rope_sin = (const float*)d_in[2];
  const float* W_qkv    = (const float*)d_in[3];
  const float* b_qkv    = (const float*)d_in[4];
  const float* W_proj   = (const float*)d_in[5];
  const float* b_proj   = (const float*)d_in[6];
  const int*   nsp      = (const int*)d_in[7];
  float* out = (float*)d_out;

  char* ws = (char*)d_ws;
  u16* Xb   = (u16*)(ws);              // 8192x768 bf16
  u16* Wqkt = (u16*)(ws + 12582912);   // 2304x768 bf16
  u16* Wpt  = (u16*)(ws + 16121856);   // 768x768 bf16
  u16* Qb   = (u16*)(ws + 55050240);   // 48x2048x64 bf16
  u16* Kb   = (u16*)(ws + 67633152);
  u16* Vtb  = (u16*)(ws + 80216064);   // 48x64x2048 bf16
  u16* att  = (u16*)(ws + 92798976);   // 8192x768 bf16

  prep<<<8448, 256, 0, stream>>>(x, Xb, W_qkv, Wqkt, W_proj, Wpt);
  gemm_qkv_rope<<<dim3(18, 64), 256, 0, stream>>>(Xb, Wqkt, b_qkv, rope_cos, rope_sin,
                                                  nsp, Qb, Kb, Vtb);
  attn<<<1536, 256, 0, stream>>>(Qb, Kb, Vtb, att);
  gemm_bt<<<dim3(6, 64), 256, 0, stream>>>(att, Wpt, b_proj, out, 8192, 768, 768);
}

// Round 10
// 237.687 us; speedup vs baseline: 1.5488x; 1.4219x over previous
//
#include <hip/hip_runtime.h>
#include <stdint.h>

typedef unsigned short u16;
typedef __bf16 bf16x8 __attribute__((ext_vector_type(8)));
typedef __bf16 bf16x2 __attribute__((ext_vector_type(2)));
typedef short s16x4 __attribute__((ext_vector_type(4)));
typedef float f32x4 __attribute__((ext_vector_type(4)));

typedef __attribute__((address_space(1))) void gvoid_t;
typedef __attribute__((address_space(3))) void lvoid_t;

struct alignas(16) U128 { uint32_t x, y, z, w; };
struct alignas(16) F128 { float x, y, z, w; };
struct alignas(8)  U64v { uint32_t x, y; };

__device__ __forceinline__ void gld16(const u16* g, u16* lds) {
  __builtin_amdgcn_global_load_lds((gvoid_t*)const_cast<u16*>(g),
                                   (lvoid_t*)lds, 16, 0, 0);
}

__device__ __forceinline__ u16 f2bf(float f) {
  uint32_t u = __builtin_bit_cast(uint32_t, f);
  u += 0x7FFFu + ((u >> 16) & 1u);   // RNE
  return (u16)(u >> 16);
}
__device__ __forceinline__ float bf2f(u16 h) {
  return __builtin_bit_cast(float, (uint32_t)h << 16);
}
__device__ __forceinline__ bf16x8 ldfrag(const u16* p) {
  U128 u = *reinterpret_cast<const U128*>(p);
  return __builtin_bit_cast(bf16x8, u);
}
// concat two 4x-bf16 halves into one 8x-bf16 MFMA fragment (no shuffles)
__device__ __forceinline__ bf16x8 cat8(U64v lo, U64v hi) {
  U128 u; u.x = lo.x; u.y = lo.y; u.z = hi.x; u.w = hi.y;
  return __builtin_bit_cast(bf16x8, u);
}
// pack two f32 -> bf16x2 dword via HW cvt (compiler emits v_cvt_pk_bf16_f32)
__device__ __forceinline__ uint32_t pkbf(float a, float b) {
  bf16x2 v;
  v[0] = (__bf16)a;
  v[1] = (__bf16)b;
  return __builtin_bit_cast(uint32_t, v);
}

// raw v_exp_f32 (exp2) — scores bounded (|s|<~10), no denormal concerns
__device__ __forceinline__ float EXP2(float x) { return __builtin_amdgcn_exp2f(x); }

// ---------------- fused prep: fp32->bf16 convert (x) + both weight transposes -------
__global__ void prep(const float* __restrict__ x, u16* __restrict__ Xb,
                     const float* __restrict__ Wq, u16* __restrict__ Wqkt,
                     const float* __restrict__ Wp, u16* __restrict__ Wpt) {
  const int id = blockIdx.x;
  const int tid = threadIdx.x;
  if (id < 6144) {
    int i = (id * 256 + tid) * 4;
    F128 v = *reinterpret_cast<const F128*>(x + i);
    U64v o;
    o.x = (uint32_t)f2bf(v.x) | ((uint32_t)f2bf(v.y) << 16);
    o.y = (uint32_t)f2bf(v.z) | ((uint32_t)f2bf(v.w) << 16);
    *reinterpret_cast<U64v*>(Xb + i) = o;
    return;
  }
  __shared__ float T[32][33];
  const float* W; u16* Wt; int K, N, n0, k0;
  if (id < 7872) {
    int e = id - 6144; W = Wq; Wt = Wqkt; K = 768; N = 2304;
    n0 = (e % 72) * 32; k0 = (e / 72) * 32;
  } else {
    int e = id - 7872; W = Wp; Wt = Wpt; K = 768; N = 768;
    n0 = (e % 24) * 32; k0 = (e / 24) * 32;
  }
#pragma unroll
  for (int i = 0; i < 4; ++i) {
    int e = i * 256 + tid, r = e >> 5, c = e & 31;
    T[r][c] = W[(size_t)(k0 + r) * N + n0 + c];
  }
  __syncthreads();
#pragma unroll
  for (int i = 0; i < 4; ++i) {
    int e = i * 256 + tid, r = e >> 5, c = e & 31;
    Wt[(size_t)(n0 + r) * K + k0 + c] = f2bf(T[c][r]);
  }
}

// =====================================================================================
// 4-wave GEMM: BM=BN=128, BK=32, 3-slot cyclic LDS (48 KB -> 3 blocks/CU), counted
// vmcnt, XCD-swizzled grid. R7-measured best-known GEMM structure for this shape.
// =====================================================================================

#define GEMM_PIPE(A_, Bt_, KD_, NKT_)                                                \
  const int tid = threadIdx.x;                                                       \
  const int wave = tid >> 6, lane = tid & 63;                                        \
  const int quad = lane >> 4, l16 = lane & 15;                                       \
  const int m0 = by * 128, n0 = bx * 128;                                            \
  const int wr = (wave & 1) * 64, wc = (wave >> 1) * 64;                             \
  f32x4 acc[4][4];                                                                   \
  _Pragma("unroll")                                                                  \
  for (int i = 0; i < 4; ++i)                                                        \
    _Pragma("unroll")                                                                \
    for (int j = 0; j < 4; ++j) acc[i][j] = (f32x4){0.f, 0.f, 0.f, 0.f};             \
  const int c0 = wave * 128 + lane;                                                  \
  const int row0 = c0 >> 2, kq0 = c0 & 3;                                            \
  const int c1 = c0 + 64;                                                            \
  const int row1 = c1 >> 2, kq1 = c1 & 3;                                            \
  const u16* Ag0 = (A_) + (size_t)(m0 + row0) * (KD_) + kq0 * 8;                     \
  const u16* Ag1 = (A_) + (size_t)(m0 + row1) * (KD_) + kq1 * 8;                     \
  const u16* Bg0 = (Bt_) + (size_t)(n0 + row0) * (KD_) + kq0 * 8;                    \
  const u16* Bg1 = (Bt_) + (size_t)(n0 + row1) * (KD_) + kq1 * 8;                    \
  STG(0, 0);                                                                         \
  STG(1, 1);                                                                         \
  for (int t = 0; t < (NKT_); ++t) {                                                 \
    __builtin_amdgcn_sched_barrier(0);                                               \
    if (t < (NKT_) - 1) asm volatile("s_waitcnt vmcnt(4)" ::: "memory");             \
    else                asm volatile("s_waitcnt vmcnt(0)" ::: "memory");             \
    __builtin_amdgcn_sched_barrier(0);                                               \
    __builtin_amdgcn_s_barrier();                                                    \
    __builtin_amdgcn_sched_barrier(0);                                               \
    if (t + 2 < (NKT_)) STG(t + 2, (t + 2) % 3);                                     \
    const u16* Ab = Asl + (t % 3) * 4096;                                            \
    const u16* Bb = Bsl + (t % 3) * 4096;                                            \
    bf16x8 af[4], bfr[4];                                                            \
    _Pragma("unroll")                                                                \
    for (int rb = 0; rb < 4; ++rb)                                                   \
      af[rb] = ldfrag(&Ab[(wr + rb * 16 + l16) * 32 + quad * 8]);                    \
    _Pragma("unroll")                                                                \
    for (int cb = 0; cb < 4; ++cb)                                                   \
      bfr[cb] = ldfrag(&Bb[(wc + cb * 16 + l16) * 32 + quad * 8]);                   \
    __builtin_amdgcn_s_setprio(1);                                                   \
    _Pragma("unroll")                                                                \
    for (int rb = 0; rb < 4; ++rb)                                                   \
      _Pragma("unroll")                                                              \
      for (int cb = 0; cb < 4; ++cb)                                                 \
        acc[rb][cb] = __builtin_amdgcn_mfma_f32_16x16x32_bf16(                       \
            af[rb], bfr[cb], acc[rb][cb], 0, 0, 0);                                  \
    __builtin_amdgcn_s_setprio(0);                                                   \
  }

#define STG(t_, s_)                                                                  \
  do {                                                                               \
    const int k0_ = (t_) * 32;                                                       \
    gld16(Ag0 + k0_, &Asl[(s_) * 4096 + wave * 1024]);                               \
    gld16(Bg0 + k0_, &Bsl[(s_) * 4096 + wave * 1024]);                               \
    gld16(Ag1 + k0_, &Asl[(s_) * 4096 + wave * 1024 + 512]);                         \
    gld16(Bg1 + k0_, &Bsl[(s_) * 4096 + wave * 1024 + 512]);                         \
  } while (0)

// ---------------- proj GEMM: C[M,N] = A[M,K] * Bt[N,K]^T + bias (f32 out) -----------
__global__ __launch_bounds__(256, 3)
void gemm_bt(const u16* __restrict__ A, const u16* __restrict__ Bt,
             const float* __restrict__ bias, float* __restrict__ C,
             int M, int N, int Karg) {
  (void)M; (void)Karg;
  __shared__ u16 Asl[3 * 4096];
  __shared__ u16 Bsl[3 * 4096];
  const int orig = blockIdx.y * 6 + blockIdx.x;
  const int swz = (orig % 8) * 48 + orig / 8;
  const int bx = swz % 6, by = swz / 6;
  GEMM_PIPE(A, Bt, 768, 24)
#pragma unroll
  for (int cb = 0; cb < 4; ++cb) {
    int col = n0 + wc + cb * 16 + l16;
    float bv = bias[col];
#pragma unroll
    for (int rb = 0; rb < 4; ++rb) {
#pragma unroll
      for (int r = 0; r < 4; ++r) {
        int row = m0 + wr + rb * 16 + quad * 4 + r;
        C[(size_t)row * N + col] = acc[rb][cb][r] + bv;
      }
    }
  }
}

// ---------------- fused QKV GEMM + bias + RoPE + scatter ----------------------------
__global__ __launch_bounds__(256, 3)
void gemm_qkv_rope(const u16* __restrict__ A, const u16* __restrict__ Bt,
                   const float* __restrict__ bias,
                   const float* __restrict__ cosT, const float* __restrict__ sinT,
                   const int* __restrict__ nsp,
                   u16* __restrict__ Qo, u16* __restrict__ Ko, u16* __restrict__ Vto) {
  __shared__ u16 Asl[3 * 4096];
  __shared__ u16 Bsl[3 * 4096];
  const int orig = blockIdx.y * 18 + blockIdx.x;
  const int swz = (orig % 8) * 144 + orig / 8;
  const int bx = swz % 18, by = swz / 18;
  GEMM_PIPE(A, Bt, 768, 24)

  const int sec = bx / 6;                  // 0=Q, 1=K, 2=V
  const int gcol0 = n0 + wc;               // 64-aligned: one head per wave
  const int hh = (gcol0 >> 6) % 12;
  const int bb = m0 >> 11;
  const int nbase = m0 & 2047;
  const int bh = bb * 12 + hh;
  const int num_special = nsp[0];
  const float QS = 0.125f * 1.4426950408889634f;  // D^-0.5 * log2e

  if (sec < 2) {
    u16* outp = sec ? Ko : Qo;
    const float qs = sec ? 1.0f : QS;
#pragma unroll
    for (int cbp = 0; cbp < 2; ++cbp) {
      const int d1 = cbp * 16 + l16;
      const int d2 = d1 + 32;
      const float bv1 = bias[gcol0 + d1];
      const float bv2 = bias[gcol0 + d2];
#pragma unroll
      for (int rb = 0; rb < 4; ++rb) {
#pragma unroll
        for (int r = 0; r < 4; ++r) {
          const int n = nbase + wr + rb * 16 + quad * 4 + r;
          float v1 = acc[rb][cbp][r] + bv1;
          float v2 = acc[rb][cbp + 2][r] + bv2;
          float o1, o2;
          if (n < num_special) {
            o1 = v1; o2 = v2;
          } else {
            int ns = n - num_special;
            float c1 = cosT[ns * 64 + d1], s1 = sinT[ns * 64 + d1];
            float c2 = cosT[ns * 64 + d2], s2 = sinT[ns * 64 + d2];
            o1 = v1 * c1 - v2 * s1;
            o2 = v2 * c2 + v1 * s2;
          }
          size_t ob = ((size_t)bh * 2048 + n) * 64;
          outp[ob + d1] = f2bf(o1 * qs);
          outp[ob + d2] = f2bf(o2 * qs);
        }
      }
    }
  } else {
#pragma unroll
    for (int cb = 0; cb < 4; ++cb) {
      const int d = cb * 16 + l16;
      const float bv = bias[gcol0 + d];
#pragma unroll
      for (int rb = 0; rb < 4; ++rb) {
        const int nr = nbase + wr + rb * 16 + quad * 4;
        U64v o;
        o.x = (uint32_t)f2bf(acc[rb][cb][0] + bv) |
              ((uint32_t)f2bf(acc[rb][cb][1] + bv) << 16);
        o.y = (uint32_t)f2bf(acc[rb][cb][2] + bv) |
              ((uint32_t)f2bf(acc[rb][cb][3] + bv) << 16);
        *(U64v*)&Vto[((size_t)bh * 64 + d) * 2048 + nr] = o;
      }
    }
  }
}

// ---------------- flash attention: pair-PV at K=32, 3-slot LDS, V stays in LDS -----
// Single launch, grid 1536 = qt*48 + bh. 4 waves; wave owns keys [wave*16,+16).
// 3 LDS slots (48 KB -> still 3 blocks/CU): at PV time BOTH tiles of pair {2j,2j+1}
// are LDS-resident, so PV reads V via ds_read_b64 -> NO V registers (R8/R9 spilled
// holding vE/vO; live-across-barrier state is now pfE only, 8 VGPR < R3 baseline).
// Cadence (1 barrier/body):
//   body even t: STAGE(t+1 -> slot (t+1)%3) [t>=2], STAGE(t+2 -> slot (t+2)%3);
//                QK(slot t%3) -> pfE; sync.
//   body odd  t: QK(slot t%3) -> pfO; PV@K=32: A=cat8(pfE,pfO),
//                B=cat8(V_even from slot (t-1)%3, V_odd from slot t%3); sync.
// Hazard table (verified bodies 0..4): staged slots' last readers are QK(t-2)+
// PV(t-1), both behind the end-of-body-(t-1) barrier; end-of-body sync drains gld16.
// k-position quad*8+e -> (tile e<4?even:odd, key quad*4+(e&3)) on BOTH operands.
// MFMA/pair: 16 QK + 16 PV = 32 (was 48 with K=16 PV).
__global__ __launch_bounds__(256, 3)
void attn(const u16* __restrict__ Q, const u16* __restrict__ Kg,
          const u16* __restrict__ Vt, u16* __restrict__ Out) {
  __shared__ u16 smem2[3 * 8192];    // 48 KB: 3 slots x [K 64x64 | V 64x64]
  __shared__ float invS[64];
  const int tid = threadIdx.x;
  const int wave = tid >> 6, lane = tid & 63;
  const int quad = lane >> 4, l16 = lane & 15;
  const int idx = blockIdx.x;
  const int bh = idx % 48, qt = idx / 48;
  const int b = bh / 12, h = bh % 12;
  const u16* Qb = Q + (size_t)bh * 2048 * 64;
  const u16* Kb = Kg + (size_t)bh * 2048 * 64;
  const u16* Vb = Vt + (size_t)bh * 64 * 2048;
  const int wkey0 = wave * 16;

  const int lrow = lane >> 3;
  const int lch  = (lane & 7) ^ (lrow & 7);
  const int r0a = wave * 8;
  const int r0b = 32 + wave * 8;
  const int ksrc_a = (r0a + lrow) * 64 + lch * 8;
  const int ksrc_b = (r0b + lrow) * 64 + lch * 8;
  const size_t vsrc_a = (size_t)(r0a + lrow) * 2048 + lch * 8;
  const size_t vsrc_b = (size_t)(r0b + lrow) * 2048 + lch * 8;

  const int krd = (wkey0 + l16) * 64 + ((quad ^ (l16 & 7)) << 3);
  int vrd[4];
#pragma unroll
  for (int db = 0; db < 4; ++db)
    vrd[db] = (db * 16 + l16) * 64 +
              ((((wave << 1) | (quad >> 1)) ^ (l16 & 7)) << 3) + (quad & 1) * 4;

#define STAGE_A(kt_, s_)                                                      \
  do {                                                                        \
    u16* Kd = smem2 + (s_) * 8192;                                            \
    u16* Vd = Kd + 4096;                                                      \
    const u16* Ksrc = Kb + (size_t)(kt_) * 4096;                              \
    const u16* Vsrc = Vb + (kt_) * 64;                                        \
    gld16(Ksrc + ksrc_a, Kd + r0a * 64);                                      \
    gld16(Ksrc + ksrc_b, Kd + r0b * 64);                                      \
    gld16(Vsrc + vsrc_a, Vd + r0a * 64);                                      \
    gld16(Vsrc + vsrc_b, Vd + r0b * 64);                                      \
  } while (0)

#define QK_TILE(Ksh_, pf_)                                                    \
  do {                                                                        \
    bf16x8 ka0_ = ldfrag((Ksh_) + krd);                                       \
    bf16x8 ka1_ = ldfrag((Ksh_) + (krd ^ 32));                                \
    _Pragma("unroll")                                                         \
    for (int m = 0; m < 4; ++m) {                                             \
      f32x4 st = (f32x4){0.f, 0.f, 0.f, 0.f};                                 \
      st = __builtin_amdgcn_mfma_f32_16x16x32_bf16(ka0_, qf[m][0], st, 0, 0, 0); \
      st = __builtin_amdgcn_mfma_f32_16x16x32_bf16(ka1_, qf[m][1], st, 0, 0, 0); \
      float p0 = EXP2(st[0]), p1 = EXP2(st[1]), p2 = EXP2(st[2]), p3 = EXP2(st[3]); \
      psum[m] += (p0 + p1) + (p2 + p3);                                       \
      U64v pd_; pd_.x = pkbf(p0, p1); pd_.y = pkbf(p2, p3);                   \
      (pf_)[m] = pd_;                                                         \
    }                                                                         \
  } while (0)

  // Q fragments: direct global load (one-time; reused 32x)
  bf16x8 qf[4][2];
#pragma unroll
  for (int m = 0; m < 4; ++m) {
    const u16* qp = Qb + (size_t)(qt * 64 + m * 16 + l16) * 64 + quad * 8;
    qf[m][0] = ldfrag(qp);
    qf[m][1] = ldfrag(qp + 32);
  }

  f32x4 oacc[4][4];
#pragma unroll
  for (int m = 0; m < 4; ++m)
#pragma unroll
    for (int db = 0; db < 4; ++db) oacc[m][db] = (f32x4){0.f, 0.f, 0.f, 0.f};
  float psum[4] = {0.f, 0.f, 0.f, 0.f};

  U64v pfE[4], pfO[4];

  STAGE_A(0, 0);
  STAGE_A(1, 1);
  __syncthreads();

  for (int j = 0; j < 16; ++j) {
    const int t0 = 2 * j;
    const int sE = t0 % 3;                 // slot of even tile (cycles 0,2,1,...)
    const int sO = (t0 + 1) % 3;
    // ---- body even: stage t0+1 (j>0; j==0 staged in prologue) and t0+2 ----
    if (t0 >= 2) STAGE_A(t0 + 1, sO);
    if (t0 + 2 < 32) STAGE_A(t0 + 2, (t0 + 2) % 3);
    const u16* KshE = smem2 + sE * 8192;
    QK_TILE(KshE, pfE);
    __syncthreads();                       // drains stages; slot sE QK-read done
    // ---- body odd: QK(odd) + PV(pair) with V straight from LDS ----
    const u16* KshO = smem2 + sO * 8192;
    QK_TILE(KshO, pfO);
    bf16x8 pa0 = cat8(pfE[0], pfO[0]);
    bf16x8 pa1 = cat8(pfE[1], pfO[1]);
    bf16x8 pa2 = cat8(pfE[2], pfO[2]);
    bf16x8 pa3 = cat8(pfE[3], pfO[3]);
    const u16* VshE = KshE + 4096;
    const u16* VshO = KshO + 4096;
#pragma unroll
    for (int db = 0; db < 4; ++db) {
      U64v vlo = *(const U64v*)(VshE + vrd[db]);
      U64v vhi = *(const U64v*)(VshO + vrd[db]);
      bf16x8 vf8 = cat8(vlo, vhi);
      oacc[0][db] = __builtin_amdgcn_mfma_f32_16x16x32_bf16(pa0, vf8, oacc[0][db], 0, 0, 0);
      oacc[1][db] = __builtin_amdgcn_mfma_f32_16x16x32_bf16(pa1, vf8, oacc[1][db], 0, 0, 0);
      oacc[2][db] = __builtin_amdgcn_mfma_f32_16x16x32_bf16(pa2, vf8, oacc[2][db], 0, 0, 0);
      oacc[3][db] = __builtin_amdgcn_mfma_f32_16x16x32_bf16(pa3, vf8, oacc[3][db], 0, 0, 0);
    }
    __syncthreads();                       // slots sE,sO reads done for this pair
  }
#undef STAGE_A
#undef QK_TILE

  // ---- epilogue: cross-wave reductions ----
#pragma unroll
  for (int m = 0; m < 4; ++m) {
    psum[m] += __shfl_xor(psum[m], 16, 64);
    psum[m] += __shfl_xor(psum[m], 32, 64);
  }
  __syncthreads();
  float* LS = (float*)smem2;
  if (quad == 0) {
#pragma unroll
    for (int m = 0; m < 4; ++m) LS[wave * 64 + m * 16 + l16] = psum[m];
  }
  __syncthreads();
  if (tid < 64) {
    float tot = LS[tid] + LS[64 + tid] + LS[128 + tid] + LS[192 + tid];
    invS[tid] = 1.0f / tot;
  }

  float* OR = (float*)smem2;       // 18432 B < 48 KB
  const int q = tid >> 2;
  const int d0 = (tid & 3) * 4;
  const size_t obase = ((size_t)(b * 2048 + qt * 64 + q)) * 768 + h * 64 + d0;
#pragma unroll
  for (int db = 0; db < 4; ++db) {
    __syncthreads();
#pragma unroll
    for (int m = 0; m < 4; ++m)
#pragma unroll
      for (int r = 0; r < 4; ++r)
        OR[(wave * 64 + m * 16 + quad * 4 + r) * 18 + l16] = oacc[m][db][r];
    __syncthreads();
    float s0 = 0.f, s1 = 0.f, s2 = 0.f, s3 = 0.f;
#pragma unroll
    for (int w = 0; w < 4; ++w) {
      const float* p = &OR[(w * 64 + q) * 18 + d0];
      s0 += p[0]; s1 += p[1]; s2 += p[2]; s3 += p[3];
    }
    float iv = invS[q];
    U64v o;
    o.x = (uint32_t)f2bf(s0 * iv) | ((uint32_t)f2bf(s1 * iv) << 16);
    o.y = (uint32_t)f2bf(s2 * iv) | ((uint32_t)f2bf(s3 * iv) << 16);
    *(U64v*)&Out[obase + db * 16] = o;
  }
}

extern "C" void kernel_launch(void* const* d_in, const int* in_sizes, int n_in,
                              void* d_out, int out_size, void* d_ws, size_t ws_size,
                              hipStream_t stream) {
  (void)in_sizes; (void)n_in; (void)out_size; (void)ws_size;
  const float* x        = (const float*)d_in[0];
  const float* rope_cos = (const float*)d_in[1];
  const float* rope_sin = (const float*)d_in[2];
  const float* W_qkv    = (const float*)d_in[3];
  const float* b_qkv    = (const float*)d_in[4];
  const float* W_proj   = (const float*)d_in[5];
  const float* b_proj   = (const float*)d_in[6];
  const int*   nsp      = (const int*)d_in[7];
  float* out = (float*)d_out;

  char* ws = (char*)d_ws;
  u16* Xb   = (u16*)(ws);              // 8192x768 bf16
  u16* Wqkt = (u16*)(ws + 12582912);   // 2304x768 bf16
  u16* Wpt  = (u16*)(ws + 16121856);   // 768x768 bf16
  u16* Qb   = (u16*)(ws + 55050240);   // 48x2048x64 bf16
  u16* Kb   = (u16*)(ws + 67633152);
  u16* Vtb  = (u16*)(ws + 80216064);   // 48x64x2048 bf16
  u16* att  = (u16*)(ws + 92798976);   // 8192x768 bf16

  prep<<<8448, 256, 0, stream>>>(x, Xb, W_qkv, Wqkt, W_proj, Wpt);
  gemm_qkv_rope<<<dim3(18, 64), 256, 0, stream>>>(Xb, Wqkt, b_qkv, rope_cos, rope_sin,
                                                  nsp, Qb, Kb, Vtb);
  attn<<<1536, 256, 0, stream>>>(Qb, Kb, Vtb, att);
  gemm_bt<<<dim3(6, 64), 256, 0, stream>>>(att, Wpt, b_proj, out, 8192, 768, 768);
}

// Round 11
// 226.288 us; speedup vs baseline: 1.6268x; 1.0504x over previous
//
#include <hip/hip_runtime.h>
#include <stdint.h>

typedef unsigned short u16;
typedef __bf16 bf16x8 __attribute__((ext_vector_type(8)));
typedef __bf16 bf16x2 __attribute__((ext_vector_type(2)));
typedef short s16x4 __attribute__((ext_vector_type(4)));
typedef float f32x4 __attribute__((ext_vector_type(4)));

typedef __attribute__((address_space(1))) void gvoid_t;
typedef __attribute__((address_space(3))) void lvoid_t;

struct alignas(16) U128 { uint32_t x, y, z, w; };
struct alignas(16) F128 { float x, y, z, w; };
struct alignas(8)  U64v { uint32_t x, y; };

__device__ __forceinline__ void gld16(const u16* g, u16* lds) {
  __builtin_amdgcn_global_load_lds((gvoid_t*)const_cast<u16*>(g),
                                   (lvoid_t*)lds, 16, 0, 0);
}

__device__ __forceinline__ u16 f2bf(float f) {
  uint32_t u = __builtin_bit_cast(uint32_t, f);
  u += 0x7FFFu + ((u >> 16) & 1u);   // RNE
  return (u16)(u >> 16);
}
__device__ __forceinline__ float bf2f(u16 h) {
  return __builtin_bit_cast(float, (uint32_t)h << 16);
}
__device__ __forceinline__ bf16x8 ldfrag(const u16* p) {
  U128 u = *reinterpret_cast<const U128*>(p);
  return __builtin_bit_cast(bf16x8, u);
}
// concat two 4x-bf16 halves into one 8x-bf16 MFMA fragment (no shuffles)
__device__ __forceinline__ bf16x8 cat8(U64v lo, U64v hi) {
  U128 u; u.x = lo.x; u.y = lo.y; u.z = hi.x; u.w = hi.y;
  return __builtin_bit_cast(bf16x8, u);
}
// pack two f32 -> bf16x2 dword via HW cvt (compiler emits v_cvt_pk_bf16_f32)
__device__ __forceinline__ uint32_t pkbf(float a, float b) {
  bf16x2 v;
  v[0] = (__bf16)a;
  v[1] = (__bf16)b;
  return __builtin_bit_cast(uint32_t, v);
}

// raw v_exp_f32 (exp2) — scores bounded (|s|<~10), no denormal concerns
__device__ __forceinline__ float EXP2(float x) { return __builtin_amdgcn_exp2f(x); }

// ---------------- fused prep: fp32->bf16 convert (x) + both weight transposes -------
__global__ void prep(const float* __restrict__ x, u16* __restrict__ Xb,
                     const float* __restrict__ Wq, u16* __restrict__ Wqkt,
                     const float* __restrict__ Wp, u16* __restrict__ Wpt) {
  const int id = blockIdx.x;
  const int tid = threadIdx.x;
  if (id < 6144) {
    int i = (id * 256 + tid) * 4;
    F128 v = *reinterpret_cast<const F128*>(x + i);
    U64v o;
    o.x = (uint32_t)f2bf(v.x) | ((uint32_t)f2bf(v.y) << 16);
    o.y = (uint32_t)f2bf(v.z) | ((uint32_t)f2bf(v.w) << 16);
    *reinterpret_cast<U64v*>(Xb + i) = o;
    return;
  }
  __shared__ float T[32][33];
  const float* W; u16* Wt; int K, N, n0, k0;
  if (id < 7872) {
    int e = id - 6144; W = Wq; Wt = Wqkt; K = 768; N = 2304;
    n0 = (e % 72) * 32; k0 = (e / 72) * 32;
  } else {
    int e = id - 7872; W = Wp; Wt = Wpt; K = 768; N = 768;
    n0 = (e % 24) * 32; k0 = (e / 24) * 32;
  }
#pragma unroll
  for (int i = 0; i < 4; ++i) {
    int e = i * 256 + tid, r = e >> 5, c = e & 31;
    T[r][c] = W[(size_t)(k0 + r) * N + n0 + c];
  }
  __syncthreads();
#pragma unroll
  for (int i = 0; i < 4; ++i) {
    int e = i * 256 + tid, r = e >> 5, c = e & 31;
    Wt[(size_t)(n0 + r) * K + k0 + c] = f2bf(T[c][r]);
  }
}

// =====================================================================================
// 8-wave GEMM (occupancy experiment): BM=BN=128, BK=32, 3-slot cyclic LDS (48 KB),
// 512 threads = 8 waves (4M x 2N, wave-tile 32x64, acc[2][4]), 2 blocks/CU ->
// 16 waves/CU = 4/SIMD (vs 12/CU in the 256-thread variant). Counted vmcnt:
// 2 gld16/thread/body -> vmcnt(2) keeps tile t+1's loads in flight across the
// barrier. Same K-loop cadence / XCD swizzle as R7 (best-known).
// LDS rows 32 u16 = 64B -> wave64 ds_read_b128 conflict pattern unchanged.
// =====================================================================================

#define GEMM_PIPE(A_, Bt_, KD_, NKT_)                                                \
  const int tid = threadIdx.x;                                                       \
  const int wave = tid >> 6, lane = tid & 63;                                        \
  const int quad = lane >> 4, l16 = lane & 15;                                       \
  const int m0 = by * 128, n0 = bx * 128;                                            \
  const int wm = wave & 3, wn = wave >> 2;    /* wave-tile: rows wm*32, cols wn*64 */ \
  f32x4 acc[2][4];                                                                   \
  _Pragma("unroll")                                                                  \
  for (int i = 0; i < 2; ++i)                                                        \
    _Pragma("unroll")                                                                \
    for (int j = 0; j < 4; ++j) acc[i][j] = (f32x4){0.f, 0.f, 0.f, 0.f};             \
  const int row0 = tid >> 2, kq0 = tid & 3;                                          \
  const u16* Ag0 = (A_) + (size_t)(m0 + row0) * (KD_) + kq0 * 8;                     \
  const u16* Bg0 = (Bt_) + (size_t)(n0 + row0) * (KD_) + kq0 * 8;                    \
  STG(0, 0);                                                                         \
  STG(1, 1);                                                                         \
  for (int t = 0; t < (NKT_); ++t) {                                                 \
    __builtin_amdgcn_sched_barrier(0);                                               \
    if (t < (NKT_) - 1) asm volatile("s_waitcnt vmcnt(2)" ::: "memory");             \
    else                asm volatile("s_waitcnt vmcnt(0)" ::: "memory");             \
    __builtin_amdgcn_sched_barrier(0);                                               \
    __builtin_amdgcn_s_barrier();                                                    \
    __builtin_amdgcn_sched_barrier(0);                                               \
    if (t + 2 < (NKT_)) STG(t + 2, (t + 2) % 3);                                     \
    const u16* Ab = Asl + (t % 3) * 4096;                                            \
    const u16* Bb = Bsl + (t % 3) * 4096;                                            \
    bf16x8 af[2], bfr[4];                                                            \
    _Pragma("unroll")                                                                \
    for (int rb = 0; rb < 2; ++rb)                                                   \
      af[rb] = ldfrag(&Ab[(wm * 32 + rb * 16 + l16) * 32 + quad * 8]);               \
    _Pragma("unroll")                                                                \
    for (int cb = 0; cb < 4; ++cb)                                                   \
      bfr[cb] = ldfrag(&Bb[(wn * 64 + cb * 16 + l16) * 32 + quad * 8]);              \
    __builtin_amdgcn_s_setprio(1);                                                   \
    _Pragma("unroll")                                                                \
    for (int rb = 0; rb < 2; ++rb)                                                   \
      _Pragma("unroll")                                                              \
      for (int cb = 0; cb < 4; ++cb)                                                 \
        acc[rb][cb] = __builtin_amdgcn_mfma_f32_16x16x32_bf16(                       \
            af[rb], bfr[cb], acc[rb][cb], 0, 0, 0);                                  \
    __builtin_amdgcn_s_setprio(0);                                                   \
  }

#define STG(t_, s_)                                                                  \
  do {                                                                               \
    const int k0_ = (t_) * 32;                                                       \
    gld16(Ag0 + k0_, &Asl[(s_) * 4096 + wave * 512]);                                \
    gld16(Bg0 + k0_, &Bsl[(s_) * 4096 + wave * 512]);                                \
  } while (0)

// ---------------- proj GEMM: C[M,N] = A[M,K] * Bt[N,K]^T + bias (f32 out) -----------
__global__ __launch_bounds__(512, 4)
void gemm_bt(const u16* __restrict__ A, const u16* __restrict__ Bt,
             const float* __restrict__ bias, float* __restrict__ C,
             int M, int N, int Karg) {
  (void)M; (void)Karg;
  __shared__ u16 Asl[3 * 4096];
  __shared__ u16 Bsl[3 * 4096];
  const int orig = blockIdx.y * 6 + blockIdx.x;
  const int swz = (orig % 8) * 48 + orig / 8;
  const int bx = swz % 6, by = swz / 6;
  GEMM_PIPE(A, Bt, 768, 24)
#pragma unroll
  for (int cb = 0; cb < 4; ++cb) {
    int col = n0 + wn * 64 + cb * 16 + l16;
    float bv = bias[col];
#pragma unroll
    for (int rb = 0; rb < 2; ++rb) {
#pragma unroll
      for (int r = 0; r < 4; ++r) {
        int row = m0 + wm * 32 + rb * 16 + quad * 4 + r;
        C[(size_t)row * N + col] = acc[rb][cb][r] + bv;
      }
    }
  }
}

// ---------------- fused QKV GEMM + bias + RoPE + scatter ----------------------------
// Grid (18,64), XCD-swizzled. bx: 0-5 Q, 6-11 K, 12-17 V. Wave col-span 64 == one
// head (wn*64). RoPE pair (d, d+32) lives in acc blocks (cb, cb+2) of the SAME lane.
// Q gets D^-0.5*log2e folded in (attn softmax runs in log2 domain).
// Q,K -> (B*H, N, D) bf16; V -> transposed (B*H, D, N) bf16 (4 tokens per 8B store).
__global__ __launch_bounds__(512, 4)
void gemm_qkv_rope(const u16* __restrict__ A, const u16* __restrict__ Bt,
                   const float* __restrict__ bias,
                   const float* __restrict__ cosT, const float* __restrict__ sinT,
                   const int* __restrict__ nsp,
                   u16* __restrict__ Qo, u16* __restrict__ Ko, u16* __restrict__ Vto) {
  __shared__ u16 Asl[3 * 4096];
  __shared__ u16 Bsl[3 * 4096];
  const int orig = blockIdx.y * 18 + blockIdx.x;
  const int swz = (orig % 8) * 144 + orig / 8;
  const int bx = swz % 18, by = swz / 18;
  GEMM_PIPE(A, Bt, 768, 24)

  const int sec = bx / 6;                  // 0=Q, 1=K, 2=V
  const int gcol0 = n0 + wn * 64;          // 64-aligned: one head per wave
  const int hh = (gcol0 >> 6) % 12;
  const int bb = m0 >> 11;
  const int nbase = m0 & 2047;
  const int bh = bb * 12 + hh;
  const int num_special = nsp[0];
  const float QS = 0.125f * 1.4426950408889634f;  // D^-0.5 * log2e

  if (sec < 2) {
    u16* outp = sec ? Ko : Qo;
    const float qs = sec ? 1.0f : QS;
#pragma unroll
    for (int cbp = 0; cbp < 2; ++cbp) {
      const int d1 = cbp * 16 + l16;
      const int d2 = d1 + 32;
      const float bv1 = bias[gcol0 + d1];
      const float bv2 = bias[gcol0 + d2];
#pragma unroll
      for (int rb = 0; rb < 2; ++rb) {
#pragma unroll
        for (int r = 0; r < 4; ++r) {
          const int n = nbase + wm * 32 + rb * 16 + quad * 4 + r;
          float v1 = acc[rb][cbp][r] + bv1;
          float v2 = acc[rb][cbp + 2][r] + bv2;
          float o1, o2;
          if (n < num_special) {
            o1 = v1; o2 = v2;
          } else {
            int ns = n - num_special;
            float c1 = cosT[ns * 64 + d1], s1 = sinT[ns * 64 + d1];
            float c2 = cosT[ns * 64 + d2], s2 = sinT[ns * 64 + d2];
            o1 = v1 * c1 - v2 * s1;
            o2 = v2 * c2 + v1 * s2;
          }
          size_t ob = ((size_t)bh * 2048 + n) * 64;
          outp[ob + d1] = f2bf(o1 * qs);
          outp[ob + d2] = f2bf(o2 * qs);
        }
      }
    }
  } else {
#pragma unroll
    for (int cb = 0; cb < 4; ++cb) {
      const int d = cb * 16 + l16;
      const float bv = bias[gcol0 + d];
#pragma unroll
      for (int rb = 0; rb < 2; ++rb) {
        const int nr = nbase + wm * 32 + rb * 16 + quad * 4;
        U64v o;
        o.x = (uint32_t)f2bf(acc[rb][cb][0] + bv) |
              ((uint32_t)f2bf(acc[rb][cb][1] + bv) << 16);
        o.y = (uint32_t)f2bf(acc[rb][cb][2] + bv) |
              ((uint32_t)f2bf(acc[rb][cb][3] + bv) << 16);
        *(U64v*)&Vto[((size_t)bh * 64 + d) * 2048 + nr] = o;
      }
    }
  }
}

// ---------------- flash attention: pair-PV at K=32, 3-slot LDS, V stays in LDS -----
// (R10 config, unchanged — best measured: 77.8 us, no spill.)
__global__ __launch_bounds__(256, 3)
void attn(const u16* __restrict__ Q, const u16* __restrict__ Kg,
          const u16* __restrict__ Vt, u16* __restrict__ Out) {
  __shared__ u16 smem2[3 * 8192];    // 48 KB: 3 slots x [K 64x64 | V 64x64]
  __shared__ float invS[64];
  const int tid = threadIdx.x;
  const int wave = tid >> 6, lane = tid & 63;
  const int quad = lane >> 4, l16 = lane & 15;
  const int idx = blockIdx.x;
  const int bh = idx % 48, qt = idx / 48;
  const int b = bh / 12, h = bh % 12;
  const u16* Qb = Q + (size_t)bh * 2048 * 64;
  const u16* Kb = Kg + (size_t)bh * 2048 * 64;
  const u16* Vb = Vt + (size_t)bh * 64 * 2048;
  const int wkey0 = wave * 16;

  const int lrow = lane >> 3;
  const int lch  = (lane & 7) ^ (lrow & 7);
  const int r0a = wave * 8;
  const int r0b = 32 + wave * 8;
  const int ksrc_a = (r0a + lrow) * 64 + lch * 8;
  const int ksrc_b = (r0b + lrow) * 64 + lch * 8;
  const size_t vsrc_a = (size_t)(r0a + lrow) * 2048 + lch * 8;
  const size_t vsrc_b = (size_t)(r0b + lrow) * 2048 + lch * 8;

  const int krd = (wkey0 + l16) * 64 + ((quad ^ (l16 & 7)) << 3);
  int vrd[4];
#pragma unroll
  for (int db = 0; db < 4; ++db)
    vrd[db] = (db * 16 + l16) * 64 +
              ((((wave << 1) | (quad >> 1)) ^ (l16 & 7)) << 3) + (quad & 1) * 4;

#define STAGE_A(kt_, s_)                                                      \
  do {                                                                        \
    u16* Kd = smem2 + (s_) * 8192;                                            \
    u16* Vd = Kd + 4096;                                                      \
    const u16* Ksrc = Kb + (size_t)(kt_) * 4096;                              \
    const u16* Vsrc = Vb + (kt_) * 64;                                        \
    gld16(Ksrc + ksrc_a, Kd + r0a * 64);                                      \
    gld16(Ksrc + ksrc_b, Kd + r0b * 64);                                      \
    gld16(Vsrc + vsrc_a, Vd + r0a * 64);                                      \
    gld16(Vsrc + vsrc_b, Vd + r0b * 64);                                      \
  } while (0)

#define QK_TILE(Ksh_, pf_)                                                    \
  do {                                                                        \
    bf16x8 ka0_ = ldfrag((Ksh_) + krd);                                       \
    bf16x8 ka1_ = ldfrag((Ksh_) + (krd ^ 32));                                \
    _Pragma("unroll")                                                         \
    for (int m = 0; m < 4; ++m) {                                             \
      f32x4 st = (f32x4){0.f, 0.f, 0.f, 0.f};                                 \
      st = __builtin_amdgcn_mfma_f32_16x16x32_bf16(ka0_, qf[m][0], st, 0, 0, 0); \
      st = __builtin_amdgcn_mfma_f32_16x16x32_bf16(ka1_, qf[m][1], st, 0, 0, 0); \
      float p0 = EXP2(st[0]), p1 = EXP2(st[1]), p2 = EXP2(st[2]), p3 = EXP2(st[3]); \
      psum[m] += (p0 + p1) + (p2 + p3);                                       \
      U64v pd_; pd_.x = pkbf(p0, p1); pd_.y = pkbf(p2, p3);                   \
      (pf_)[m] = pd_;                                                         \
    }                                                                         \
  } while (0)

  bf16x8 qf[4][2];
#pragma unroll
  for (int m = 0; m < 4; ++m) {
    const u16* qp = Qb + (size_t)(qt * 64 + m * 16 + l16) * 64 + quad * 8;
    qf[m][0] = ldfrag(qp);
    qf[m][1] = ldfrag(qp + 32);
  }

  f32x4 oacc[4][4];
#pragma unroll
  for (int m = 0; m < 4; ++m)
#pragma unroll
    for (int db = 0; db < 4; ++db) oacc[m][db] = (f32x4){0.f, 0.f, 0.f, 0.f};
  float psum[4] = {0.f, 0.f, 0.f, 0.f};

  U64v pfE[4], pfO[4];

  STAGE_A(0, 0);
  STAGE_A(1, 1);
  __syncthreads();

  for (int j = 0; j < 16; ++j) {
    const int t0 = 2 * j;
    const int sE = t0 % 3;
    const int sO = (t0 + 1) % 3;
    if (t0 >= 2) STAGE_A(t0 + 1, sO);
    if (t0 + 2 < 32) STAGE_A(t0 + 2, (t0 + 2) % 3);
    const u16* KshE = smem2 + sE * 8192;
    QK_TILE(KshE, pfE);
    __syncthreads();
    const u16* KshO = smem2 + sO * 8192;
    QK_TILE(KshO, pfO);
    bf16x8 pa0 = cat8(pfE[0], pfO[0]);
    bf16x8 pa1 = cat8(pfE[1], pfO[1]);
    bf16x8 pa2 = cat8(pfE[2], pfO[2]);
    bf16x8 pa3 = cat8(pfE[3], pfO[3]);
    const u16* VshE = KshE + 4096;
    const u16* VshO = KshO + 4096;
#pragma unroll
    for (int db = 0; db < 4; ++db) {
      U64v vlo = *(const U64v*)(VshE + vrd[db]);
      U64v vhi = *(const U64v*)(VshO + vrd[db]);
      bf16x8 vf8 = cat8(vlo, vhi);
      oacc[0][db] = __builtin_amdgcn_mfma_f32_16x16x32_bf16(pa0, vf8, oacc[0][db], 0, 0, 0);
      oacc[1][db] = __builtin_amdgcn_mfma_f32_16x16x32_bf16(pa1, vf8, oacc[1][db], 0, 0, 0);
      oacc[2][db] = __builtin_amdgcn_mfma_f32_16x16x32_bf16(pa2, vf8, oacc[2][db], 0, 0, 0);
      oacc[3][db] = __builtin_amdgcn_mfma_f32_16x16x32_bf16(pa3, vf8, oacc[3][db], 0, 0, 0);
    }
    __syncthreads();
  }
#undef STAGE_A
#undef QK_TILE

#pragma unroll
  for (int m = 0; m < 4; ++m) {
    psum[m] += __shfl_xor(psum[m], 16, 64);
    psum[m] += __shfl_xor(psum[m], 32, 64);
  }
  __syncthreads();
  float* LS = (float*)smem2;
  if (quad == 0) {
#pragma unroll
    for (int m = 0; m < 4; ++m) LS[wave * 64 + m * 16 + l16] = psum[m];
  }
  __syncthreads();
  if (tid < 64) {
    float tot = LS[tid] + LS[64 + tid] + LS[128 + tid] + LS[192 + tid];
    invS[tid] = 1.0f / tot;
  }

  float* OR = (float*)smem2;
  const int q = tid >> 2;
  const int d0 = (tid & 3) * 4;
  const size_t obase = ((size_t)(b * 2048 + qt * 64 + q)) * 768 + h * 64 + d0;
#pragma unroll
  for (int db = 0; db < 4; ++db) {
    __syncthreads();
#pragma unroll
    for (int m = 0; m < 4; ++m)
#pragma unroll
      for (int r = 0; r < 4; ++r)
        OR[(wave * 64 + m * 16 + quad * 4 + r) * 18 + l16] = oacc[m][db][r];
    __syncthreads();
    float s0 = 0.f, s1 = 0.f, s2 = 0.f, s3 = 0.f;
#pragma unroll
    for (int w = 0; w < 4; ++w) {
      const float* p = &OR[(w * 64 + q) * 18 + d0];
      s0 += p[0]; s1 += p[1]; s2 += p[2]; s3 += p[3];
    }
    float iv = invS[q];
    U64v o;
    o.x = (uint32_t)f2bf(s0 * iv) | ((uint32_t)f2bf(s1 * iv) << 16);
    o.y = (uint32_t)f2bf(s2 * iv) | ((uint32_t)f2bf(s3 * iv) << 16);
    *(U64v*)&Out[obase + db * 16] = o;
  }
}

extern "C" void kernel_launch(void* const* d_in, const int* in_sizes, int n_in,
                              void* d_out, int out_size, void* d_ws, size_t ws_size,
                              hipStream_t stream) {
  (void)in_sizes; (void)n_in; (void)out_size; (void)ws_size;
  const float* x        = (const float*)d_in[0];
  const float* rope_cos = (const float*)d_in[1];
  const float* rope_sin = (const float*)d_in[2];
  const float* W_qkv    = (const float*)d_in[3];
  const float* b_qkv    = (const float*)d_in[4];
  const float* W_proj   = (const float*)d_in[5];
  const float* b_proj   = (const float*)d_in[6];
  const int*   nsp      = (const int*)d_in[7];
  float* out = (float*)d_out;

  char* ws = (char*)d_ws;
  u16* Xb   = (u16*)(ws);              // 8192x768 bf16
  u16* Wqkt = (u16*)(ws + 12582912);   // 2304x768 bf16
  u16* Wpt  = (u16*)(ws + 16121856);   // 768x768 bf16
  u16* Qb   = (u16*)(ws + 55050240);   // 48x2048x64 bf16
  u16* Kb   = (u16*)(ws + 67633152);
  u16* Vtb  = (u16*)(ws + 80216064);   // 48x64x2048 bf16
  u16* att  = (u16*)(ws + 92798976);   // 8192x768 bf16

  prep<<<8448, 256, 0, stream>>>(x, Xb, W_qkv, Wqkt, W_proj, Wpt);
  gemm_qkv_rope<<<dim3(18, 64), 512, 0, stream>>>(Xb, Wqkt, b_qkv, rope_cos, rope_sin,
                                                  nsp, Qb, Kb, Vtb);
  attn<<<1536, 256, 0, stream>>>(Qb, Kb, Vtb, att);
  gemm_bt<<<dim3(6, 64), 512, 0, stream>>>(att, Wpt, b_proj, out, 8192, 768, 768);
}